// Round 7
// baseline (191.756 us; speedup 1.0000x reference)
//
#include <hip/hip_runtime.h>
#include <hip/hip_bf16.h>

#define TT 4
#define BB 16
#define CC 512
#define NN 256

typedef short short8 __attribute__((ext_vector_type(8)));
typedef _Float16 h8 __attribute__((ext_vector_type(8)));
typedef float f32x4 __attribute__((ext_vector_type(4)));
typedef float fl4 __attribute__((ext_vector_type(4)));
typedef unsigned short us4 __attribute__((ext_vector_type(4)));

__device__ __forceinline__ unsigned short bf_hi(float x) {
    unsigned u = __float_as_uint(x);
    return (unsigned short)((u + 0x7FFFu + ((u >> 16) & 1u)) >> 16);
}
__device__ __forceinline__ float bf_f(unsigned short h) {
    return __uint_as_float(((unsigned)h) << 16);
}
__device__ __forceinline__ void glds16(const void* g, void* l) {
    __builtin_amdgcn_global_load_lds(
        (const __attribute__((address_space(1))) unsigned int*)g,
        (__attribute__((address_space(3))) unsigned int*)l, 16, 0, 0);
}
// permute 16B slots within each 64-short K-group by (key&7)  [R8-proven]
__device__ __forceinline__ int csw(int c, int rkey) {
    return (c & ~63) | ((((c >> 3) & 7) ^ (rkey & 7)) << 3) | (c & 7);
}

// ---------------------------------------------------------------------------
// prep_k: fused preprocessing.  (verbatim R10)
// ---------------------------------------------------------------------------
__global__ __launch_bounds__(256) void prep_k(
    const float* __restrict__ x,
    const float* __restrict__ w0, const float* __restrict__ w1,
    const float* __restrict__ w2, const float* __restrict__ w3,
    unsigned short* __restrict__ xh, unsigned short* __restrict__ xl,
    unsigned short* __restrict__ wsplit)
{
    const int bid = blockIdx.x;
    const int tid = threadIdx.x;
    if (bid < 4096) {
        __shared__ float Tt[64][33];
        const int tb = bid >> 6, rem = bid & 63;
        const int c0 = (rem >> 3) * 64, n0 = (rem & 7) * 32;
        const int t = tb >> 4, b = tb & 15;
        {
            int row = tid >> 2, seg = tid & 3;
            const float* sp = x + ((size_t)tb * CC + c0 + row) * NN + n0 + seg * 8;
            fl4 v0 = *(const fl4*)sp;
            fl4 v1 = *(const fl4*)(sp + 4);
#pragma unroll
            for (int j = 0; j < 4; ++j) {
                Tt[row][seg * 8 + j] = v0[j];
                Tt[row][seg * 8 + 4 + j] = v1[j];
            }
        }
        __syncthreads();
        {
            int n = tid >> 3, co = tid & 7;
            int c = c0 + co * 8;
            short8 hi, lo;
#pragma unroll
            for (int j = 0; j < 8; ++j) {
                float f = Tt[co * 8 + j][n];
                unsigned short h = bf_hi(f);
                hi[j] = (short)h;
                lo[j] = (short)bf_hi(f - bf_f(h));
            }
            int nn = n0 + n;
            int key = (nn & 1) * 4 + t;
            size_t dst = (((size_t)b * NN + nn) * TT + t) * CC
                       + (c & ~63) + (((((c >> 3) & 7) ^ (key & 7))) << 3);
            *(short8*)(xh + dst) = hi;
            *(short8*)(xl + dst) = lo;
        }
    } else {
        const int wb = bid - 4096;           // [0, 512)
        const int m = wb >> 7;
        const int idx = wb & 127;
        const float* src = (m == 0) ? w0 : (m == 1) ? w1 : (m == 2) ? w2 : w3;
        unsigned short* dh = wsplit + (size_t)m * 2 * CC * CC;
        unsigned short* dl = dh + (size_t)CC * CC;
        const int flat = idx * 2048 + tid * 8;
        const int o = flat >> 9, c = flat & 511;
        const float* sp = src + flat;
        fl4 v0 = *(const fl4*)sp;
        fl4 v1 = *(const fl4*)(sp + 4);
        short8 hi, lo;
#pragma unroll
        for (int j = 0; j < 8; ++j) {
            float f = (j < 4) ? v0[j] : v1[j - 4];
            unsigned short h = bf_hi(f);
            hi[j] = (short)h;
            lo[j] = (short)bf_hi(f - bf_f(h));
        }
        size_t dst = (size_t)o * CC + (c & ~63) + ((((c >> 3) & 7) ^ (o & 7)) << 3);
        *(short8*)(dh + dst) = hi;
        *(short8*)(dl + dst) = lo;
    }
}

// ---------------------------------------------------------------------------
// gemm_qkv_f: fused q/k/v GEMM (3-pass bf16 split) + BN + LIF + fixup.
// R17 = R16 with Ah ALSO register-direct (A rows are per-wave-disjoint and
// intra-wave reuse lives in registers, so LDS staging of A buys nothing).
// Staged LDS: Bh 8K + Bl 8K = 16 KB; LDS traffic/K-step 112->80 KB,
// glds16 per thread 8->4. 4 blocks/CU. grid 3072, block 256.
// ---------------------------------------------------------------------------
__global__ __launch_bounds__(256, 4) void gemm_qkv_f(
    const unsigned short* __restrict__ w8,
    const unsigned short* __restrict__ Bh, const unsigned short* __restrict__ Bl,
    const float* __restrict__ qg, const float* __restrict__ qb,
    const float* __restrict__ qm, const float* __restrict__ qva,
    const float* __restrict__ kg, const float* __restrict__ kbe,
    const float* __restrict__ km, const float* __restrict__ kva,
    const float* __restrict__ vg, const float* __restrict__ vb,
    const float* __restrict__ vm, const float* __restrict__ vva,
    const float* __restrict__ qw, const float* __restrict__ kw,
    const float* __restrict__ vw, const float* __restrict__ xf,
    unsigned short* __restrict__ qo, unsigned short* __restrict__ ktr,
    unsigned short* __restrict__ vtr, float* __restrict__ outv)
{
    const int bid = blockIdx.x;
    const int orig = (bid & 7) * 384 + (bid >> 3);
    const int cb = orig / 12;
    const int ob = orig - cb * 12;
    const int mat = ob >> 2;
    const int o0 = (ob & 3) * 128;
    const int col0 = cb * 64;
    const int b  = cb >> 4;
    const int n0 = (cb & 15) * 16;
    const unsigned short* Ahg = w8 + (size_t)mat * 2 * CC * CC;  // A-high, direct
    const unsigned short* Alg = Ahg + (size_t)CC * CC;           // A-low, direct

    const int tid = threadIdx.x, lane = tid & 63, wid = tid >> 6;
    const int l16 = lane & 15, kb = lane >> 4;
    const int sx = l16 & 7;

    __shared__ __align__(16) char raw[32768];   // Bh 8K | Bl 8K (+Yf 32K epi)

    // staging: 4 glds16 per wave; Bh rows 0-31/32-63, Bl rows 0-31/32-63
    const int srow = lane >> 3, sslot = lane & 7;
    const unsigned short* sect =
        (wid == 0) ? Bh + (size_t)col0 * CC :
        (wid == 1) ? Bh + (size_t)(col0 + 32) * CC :
        (wid == 2) ? Bl + (size_t)col0 * CC :
                     Bl + (size_t)(col0 + 32) * CC;
    const unsigned short* gsrc = sect + (size_t)srow * CC + sslot * 8;
    char* ldsb = raw + wid * 4096;

    f32x4 acc[2][4];
#pragma unroll
    for (int r = 0; r < 2; ++r)
#pragma unroll
        for (int c = 0; c < 4; ++c) acc[r][c] = (f32x4){0.f, 0.f, 0.f, 0.f};

    for (int ks = 0; ks < 8; ++ks) {
        const int k0 = ks * 64;
        // A fragments direct from global (per-wave-disjoint rows; ^sx
        // un-swizzles the (o&7) csw applied in prep_k).
        short8 ahv[2][2], alv[2][2];
#pragma unroll
        for (int ksub = 0; ksub < 2; ++ksub) {
            const int kof = k0 + (((ksub * 4 + kb) ^ sx) << 3);
#pragma unroll
            for (int r = 0; r < 2; ++r) {
                const size_t arow = (size_t)(o0 + wid * 32 + r * 16 + l16) * CC;
                ahv[ksub][r] = *(const short8*)(Ahg + arow + kof);
                alv[ksub][r] = *(const short8*)(Alg + arow + kof);
            }
        }
        // stage Bh/Bl into LDS
#pragma unroll
        for (int i = 0; i < 4; ++i)
            glds16(gsrc + (size_t)(i * 8) * CC + k0, ldsb + i * 1024);
        __syncthreads();
#pragma unroll
        for (int ksub = 0; ksub < 2; ++ksub) {
            const int soff = ((ksub * 4 + kb) ^ sx) << 4;
            short8 bh[4], bl[4];
#pragma unroll
            for (int c = 0; c < 4; ++c) {
                const int rb = (c * 16 + l16) * 128 + soff;
                bh[c] = *(const short8*)(raw + rb);
                bl[c] = *(const short8*)(raw + 8192 + rb);
            }
#pragma unroll
            for (int r = 0; r < 2; ++r)
#pragma unroll
                for (int c = 0; c < 4; ++c)
                    acc[r][c] = __builtin_amdgcn_mfma_f32_16x16x32_bf16(ahv[ksub][r], bh[c], acc[r][c], 0, 0, 0);
#pragma unroll
            for (int r = 0; r < 2; ++r)
#pragma unroll
                for (int c = 0; c < 4; ++c)
                    acc[r][c] = __builtin_amdgcn_mfma_f32_16x16x32_bf16(alv[ksub][r], bh[c], acc[r][c], 0, 0, 0);
#pragma unroll
            for (int r = 0; r < 2; ++r)
#pragma unroll
                for (int c = 0; c < 4; ++c)
                    acc[r][c] = __builtin_amdgcn_mfma_f32_16x16x32_bf16(ahv[ksub][r], bl[c], acc[r][c], 0, 0, 0);
        }
        __syncthreads();
    }

    // ---- epilogue: acc -> LDS y tile [128][64] (XOR-banked) ----
    float* Yf = (float*)raw;
#pragma unroll
    for (int r = 0; r < 2; ++r)
#pragma unroll
        for (int c = 0; c < 4; ++c) {
            const int col = c * 16 + l16;
#pragma unroll
            for (int g = 0; g < 4; ++g) {
                const int row = wid * 32 + r * 16 + kb * 4 + g;
                Yf[row * 64 + (col ^ (((row >> 2) & 7) << 2))] = acc[r][c][g];
            }
        }
    __syncthreads();

    const float* gg = (mat == 0) ? qg : (mat == 1) ? kg : vg;
    const float* be = (mat == 0) ? qb : (mat == 1) ? kbe : vb;
    const float* mu = (mat == 0) ? qm : (mat == 1) ? km : vm;
    const float* va = (mat == 0) ? qva : (mat == 1) ? kva : vva;
    const float* wsel = (mat == 0) ? qw : (mat == 1) ? kw : vw;

    const int lo2  = tid >> 3;
    const int rsel = (tid >> 2) & 1;
    const int ln2  = tid & 3;
    const float M1 = 2e-4f;

    float inv[2], bbv[2];
#pragma unroll
    for (int i = 0; i < 2; ++i) {
        int oo = o0 + lo2 * 4 + rsel * 2 + i;
        double invd = (double)gg[oo] / sqrt((double)va[oo] + 1e-5);
        inv[i] = (float)invd;
        bbv[i] = (float)((double)be[oo] - (double)mu[oo] * invd);
    }

    unsigned long long s1b = 0;
    unsigned fmask = 0;
#pragma unroll
    for (int i = 0; i < 2; ++i) {
        const int row = lo2 * 4 + rsel * 2 + i;
        const int rk = ((row >> 2) & 7) << 2;
#pragma unroll
        for (int j = 0; j < 4; ++j) {
            fl4 yv = *(const fl4*)&Yf[row * 64 + (((ln2 * 4 + j) * 4) ^ rk)];
            float vv = 0.f;
#pragma unroll
            for (int t = 0; t < TT; ++t) {
                float yy = yv[t] * inv[i] + bbv[i];
                vv += (yy - vv) * 0.5f;
                float d = vv - 1.0f;
                if (d < M1 && d > -M1) fmask |= 1u << (i * 4 + j);
                if (d >= 0.0f) { s1b |= 1ull << ((i * 4 + j) * 4 + t); vv = 0.f; }
            }
        }
    }

    unsigned long long ball = __ballot(fmask != 0);
    while (ball) {
        int src = __ffsll(ball) - 1;
        ball &= ball - 1;
        unsigned fm = (unsigned)__shfl((int)fmask, src);
        int slo2 = wid * 8 + (src >> 3);
        int srsel = (src >> 2) & 1, sln = src & 3;
        while (fm) {
            int cell = __ffs(fm) - 1;
            fm &= fm - 1;
            int ci = cell >> 2, cj = cell & 3;
            int oo = o0 + slo2 * 4 + srsel * 2 + ci, nn = n0 + sln * 4 + cj;
            double a0 = 0, a1 = 0, a2 = 0, a3 = 0;
            const float* wrow = wsel + (size_t)oo * CC;
            for (int c = lane; c < CC; c += 64) {
                double wv = (double)wrow[c];
                a0 += wv * (double)xf[(((size_t)(0 * BB + b) * CC + c) * NN) + nn];
                a1 += wv * (double)xf[(((size_t)(1 * BB + b) * CC + c) * NN) + nn];
                a2 += wv * (double)xf[(((size_t)(2 * BB + b) * CC + c) * NN) + nn];
                a3 += wv * (double)xf[(((size_t)(3 * BB + b) * CC + c) * NN) + nn];
            }
#pragma unroll
            for (int off = 32; off > 0; off >>= 1) {
                a0 += __shfl_xor(a0, off);
                a1 += __shfl_xor(a1, off);
                a2 += __shfl_xor(a2, off);
                a3 += __shfl_xor(a3, off);
            }
            if (lane == src) {
                double inv_ = (double)gg[oo] / sqrt((double)va[oo] + 1e-5);
                double bb_  = (double)be[oo] - (double)mu[oo] * inv_;
                s1b &= ~(0xFull << (cell * 4));
                double aa[4] = {a0, a1, a2, a3};
                double vv = 0.0;
#pragma unroll
                for (int t = 0; t < TT; ++t) {
                    double yy = aa[t] * inv_ + bb_;
                    vv += (yy - vv) * 0.5;
                    if (vv >= 1.0) { s1b |= 1ull << (cell * 4 + t); vv = 0.0; }
                }
            }
        }
    }

    // ---- stores ----
    if (mat == 0) {
#pragma unroll
        for (int t = 0; t < TT; ++t) {
            const size_t tb = (size_t)(t * BB + b);
#pragma unroll
            for (int i = 0; i < 2; ++i) {
                us4 pk;
#pragma unroll
                for (int j = 0; j < 4; ++j)
                    pk[j] = ((s1b >> ((i * 4 + j) * 4 + t)) & 1ull) ? (unsigned short)0x3C00 : (unsigned short)0;
                *(us4*)(qo + (tb * CC + o0 + lo2 * 4 + rsel * 2 + i) * NN + n0 + ln2 * 4) = pk;
            }
        }
    } else {
        unsigned short* tr = (mat == 1) ? ktr : vtr;
        unsigned short* Tss = (unsigned short*)raw;   // [4][16][136]
        __syncthreads();
#pragma unroll
        for (int t = 0; t < TT; ++t)
#pragma unroll
            for (int j = 0; j < 4; ++j) {
                unsigned p0 = ((s1b >> ((0 * 4 + j) * 4 + t)) & 1ull) ? 0x3F80u : 0u;
                unsigned p1 = ((s1b >> ((1 * 4 + j) * 4 + t)) & 1ull) ? 0x3F80u : 0u;
                *(unsigned*)&Tss[t * 2176 + (ln2 * 4 + j) * 136 + lo2 * 4 + rsel * 2] =
                    p0 | (p1 << 16);
            }
        __syncthreads();
        {
            const int nrow = tid >> 4, seg = tid & 15;
#pragma unroll
            for (int t = 0; t < TT; ++t) {
                const unsigned short* sp = Tss + t * 2176 + nrow * 136 + seg * 8;
                short8 w0 = *(const short8*)sp;
                unsigned short* dst = tr + ((size_t)(t * BB + b) * NN + n0 + nrow) * CC + o0 + seg * 8;
                *(short8*)dst = w0;
            }
        }
        if (mat == 2) {
#pragma unroll
            for (int t = 0; t < TT; ++t) {
                const size_t tb = (size_t)(t * BB + b);
#pragma unroll
                for (int i = 0; i < 2; ++i) {
                    fl4 f;
#pragma unroll
                    for (int j = 0; j < 4; ++j)
                        f[j] = ((s1b >> ((i * 4 + j) * 4 + t)) & 1ull) ? 1.f : 0.f;
                    *(fl4*)(outv + (tb * CC + o0 + lo2 * 4 + rsel * 2 + i) * NN + n0 + ln2 * 4) = f;
                }
            }
        }
    }
}

// ---------------------------------------------------------------------------
// gemm_p_f: projection GEMM (2-pass) + BN + double-LIF + fixup, fused.
// R17: Ah AND Al register-direct; only Bh staged (8 KB; decl 32K for Yf).
// grid 1024, block 256.
// ---------------------------------------------------------------------------
__global__ __launch_bounds__(256) void gemm_p_f(
    const unsigned short* __restrict__ Ah, const unsigned short* __restrict__ Al,
    const unsigned short* __restrict__ Bhb,
    const float* __restrict__ gg, const float* __restrict__ be,
    const float* __restrict__ mu, const float* __restrict__ va,
    const float* __restrict__ pb, const float* __restrict__ pw,
    const unsigned short* __restrict__ abf, float* __restrict__ out)
{
    const int bid = blockIdx.x;
    const int orig = (bid & 7) * 128 + (bid >> 3);
    const int ob = orig & 3, cb = orig >> 2;
    const int o0 = ob * 128, col0 = cb * 64;
    const int b = cb >> 4, n0 = (cb & 15) * 16;
    const int tid = threadIdx.x, lane = tid & 63, wid = tid >> 6;
    const int l16 = lane & 15, kb = lane >> 4;
    const int sx = l16 & 7;

    __shared__ __align__(16) char raw[32768];   // Bh 8K (+Yf epi)

    // staging: Bh only, 2 glds16 per wave (16 rows each)
    const int srow = lane >> 3, sslot = lane & 7;
    const unsigned short* gsrc = Bhb + (size_t)(col0 + wid * 16) * CC
                               + (size_t)srow * CC + sslot * 8;
    char* ldsb = raw + wid * 2048;

    f32x4 acc[2][4];
#pragma unroll
    for (int r = 0; r < 2; ++r)
#pragma unroll
        for (int c = 0; c < 4; ++c) acc[r][c] = (f32x4){0.f, 0.f, 0.f, 0.f};

    for (int ks = 0; ks < 8; ++ks) {
        const int k0 = ks * 64;
        short8 ahv[2][2], alv[2][2];
#pragma unroll
        for (int ksub = 0; ksub < 2; ++ksub) {
            const int kof = k0 + (((ksub * 4 + kb) ^ sx) << 3);
#pragma unroll
            for (int r = 0; r < 2; ++r) {
                const size_t arow = (size_t)(o0 + wid * 32 + r * 16 + l16) * CC;
                ahv[ksub][r] = *(const short8*)(Ah + arow + kof);
                alv[ksub][r] = *(const short8*)(Al + arow + kof);
            }
        }
#pragma unroll
        for (int i = 0; i < 2; ++i)
            glds16(gsrc + (size_t)(i * 8) * CC + k0, ldsb + i * 1024);
        __syncthreads();
#pragma unroll
        for (int ksub = 0; ksub < 2; ++ksub) {
            const int soff = ((ksub * 4 + kb) ^ sx) << 4;
            short8 bh[4];
#pragma unroll
            for (int c = 0; c < 4; ++c) {
                const int rb = (c * 16 + l16) * 128 + soff;
                bh[c] = *(const short8*)(raw + rb);
            }
#pragma unroll
            for (int r = 0; r < 2; ++r)
#pragma unroll
                for (int c = 0; c < 4; ++c)
                    acc[r][c] = __builtin_amdgcn_mfma_f32_16x16x32_bf16(ahv[ksub][r], bh[c], acc[r][c], 0, 0, 0);
#pragma unroll
            for (int r = 0; r < 2; ++r)
#pragma unroll
                for (int c = 0; c < 4; ++c)
                    acc[r][c] = __builtin_amdgcn_mfma_f32_16x16x32_bf16(alv[ksub][r], bh[c], acc[r][c], 0, 0, 0);
        }
        __syncthreads();
    }

    // ---- epilogue ----
    float* Yf = (float*)raw;
#pragma unroll
    for (int r = 0; r < 2; ++r)
#pragma unroll
        for (int c = 0; c < 4; ++c) {
            const int col = c * 16 + l16;
#pragma unroll
            for (int g = 0; g < 4; ++g) {
                const int row = wid * 32 + r * 16 + kb * 4 + g;
                Yf[row * 64 + (col ^ (((row >> 2) & 7) << 2))] = acc[r][c][g];
            }
        }
    __syncthreads();

    const int lo2  = tid >> 3;
    const int rsel = (tid >> 2) & 1;
    const int ln2  = tid & 3;
    const float M1 = 2e-4f;

    float inv[2], bbv[2], pbo[2];
#pragma unroll
    for (int i = 0; i < 2; ++i) {
        int oo = o0 + lo2 * 4 + rsel * 2 + i;
        double invd = (double)gg[oo] / sqrt((double)va[oo] + 1e-5);
        inv[i] = (float)invd;
        bbv[i] = (float)((double)be[oo] - (double)mu[oo] * invd);
        pbo[i] = pb[oo];
    }

    unsigned long long s2b = 0;
    unsigned fmask = 0;
#pragma unroll
    for (int i = 0; i < 2; ++i) {
        const int row = lo2 * 4 + rsel * 2 + i;
        const int rk = ((row >> 2) & 7) << 2;
#pragma unroll
        for (int j = 0; j < 4; ++j) {
            fl4 yv = *(const fl4*)&Yf[row * 64 + (((ln2 * 4 + j) * 4) ^ rk)];
            float vv = 0.f;
            unsigned s1loc = 0;
#pragma unroll
            for (int t = 0; t < TT; ++t) {
                float yy = (yv[t] + pbo[i]) * inv[i] + bbv[i];
                vv += (yy - vv) * 0.5f;
                float d = vv - 1.0f;
                if (d < M1 && d > -M1) fmask |= 1u << (i * 4 + j);
                if (d >= 0.0f) { s1loc |= 1u << t; vv = 0.f; }
            }
            float v2 = vv;
#pragma unroll
            for (int t = 0; t < TT; ++t) {
                float s1 = ((s1loc >> t) & 1u) ? 1.f : 0.f;
                v2 += (s1 - v2) * 0.5f;
                float d = v2 - 1.0f;
                if (d < M1 && d > -M1) fmask |= 1u << (i * 4 + j);
                if (d >= 0.0f) { s2b |= 1ull << ((i * 4 + j) * 4 + t); v2 = 0.f; }
            }
        }
    }

    unsigned long long ball = __ballot(fmask != 0);
    while (ball) {
        int src = __ffsll(ball) - 1;
        ball &= ball - 1;
        unsigned fm = (unsigned)__shfl((int)fmask, src);
        int slo2 = wid * 8 + (src >> 3);
        int srsel = (src >> 2) & 1, sln = src & 3;
        while (fm) {
            int cell = __ffs(fm) - 1;
            fm &= fm - 1;
            int ci = cell >> 2, cj = cell & 3;
            int oo = o0 + slo2 * 4 + srsel * 2 + ci, nn = n0 + sln * 4 + cj;
            double a0 = 0, a1 = 0, a2 = 0, a3 = 0;
            const float* wrow = pw + (size_t)oo * CC;
            const int key0 = (nn & 1) * 4;
            for (int c = lane; c < CC; c += 64) {
                double wv = (double)wrow[c];
                size_t rb = ((size_t)b * NN + nn) * TT;
                if (abf[(rb + 0) * CC + csw(c, key0 + 0)]) a0 += wv;
                if (abf[(rb + 1) * CC + csw(c, key0 + 1)]) a1 += wv;
                if (abf[(rb + 2) * CC + csw(c, key0 + 2)]) a2 += wv;
                if (abf[(rb + 3) * CC + csw(c, key0 + 3)]) a3 += wv;
            }
#pragma unroll
            for (int off = 32; off > 0; off >>= 1) {
                a0 += __shfl_xor(a0, off);
                a1 += __shfl_xor(a1, off);
                a2 += __shfl_xor(a2, off);
                a3 += __shfl_xor(a3, off);
            }
            if (lane == src) {
                double inv_ = (double)gg[oo] / sqrt((double)va[oo] + 1e-5);
                double bb_  = (double)be[oo] - (double)mu[oo] * inv_;
                double pb_  = (double)pb[oo];
                s2b &= ~(0xFull << (cell * 4));
                double aa[4] = {a0, a1, a2, a3};
                double vv = 0.0;
                unsigned s1loc = 0;
#pragma unroll
                for (int t = 0; t < TT; ++t) {
                    double yy = (aa[t] + pb_) * inv_ + bb_;
                    vv += (yy - vv) * 0.5;
                    if (vv >= 1.0) { s1loc |= 1u << t; vv = 0.0; }
                }
                double v2 = vv;
#pragma unroll
                for (int t = 0; t < TT; ++t) {
                    double s1 = ((s1loc >> t) & 1u) ? 1.0 : 0.0;
                    v2 += (s1 - v2) * 0.5;
                    if (v2 >= 1.0) { s2b |= 1ull << (cell * 4 + t); v2 = 0.0; }
                }
            }
        }
    }

#pragma unroll
    for (int t = 0; t < TT; ++t) {
        const size_t tb = (size_t)(t * BB + b);
#pragma unroll
        for (int i = 0; i < 2; ++i) {
            fl4 f;
#pragma unroll
            for (int j = 0; j < 4; ++j)
                f[j] = ((s2b >> ((i * 4 + j) * 4 + t)) & 1ull) ? 1.f : 0.f;
            *(fl4*)(out + (tb * CC + o0 + lo2 * 4 + rsel * 2 + i) * NN + n0 + ln2 * 4) = f;
        }
    }
}

// ---------------------------------------------------------------------------
// K2: kv[n,m] = sum_c kT[n,c] vT[m,c] (binary bf16, exact).  (verbatim)
// ---------------------------------------------------------------------------
__global__ __launch_bounds__(256) void k2_kv(
    const unsigned short* __restrict__ kt, const unsigned short* __restrict__ vt,
    unsigned short* __restrict__ kvf)
{
    const int m0 = blockIdx.x * 64, n0 = blockIdx.y * 64, tb = blockIdx.z;
    const int tid = threadIdx.x, lane = tid & 63, wid = tid >> 6;
    const int wn = wid >> 1, wm = wid & 1;
    const int l16 = lane & 15, kb = lane >> 4;
    __shared__ unsigned short Kt[64][72];
    __shared__ unsigned short Vt[64][72];
    f32x4 acc[2][2];
#pragma unroll
    for (int a = 0; a < 2; ++a)
#pragma unroll
        for (int c = 0; c < 2; ++c) acc[a][c] = (f32x4){0.f, 0.f, 0.f, 0.f};

    for (int ks = 0; ks < 8; ++ks) {
        const int c0 = ks * 64;
#pragma unroll
        for (int i = tid; i < 1024; i += 256) {
            int which = i >> 9, r = (i >> 3) & 63, s = i & 7;
            const unsigned short* sp = (which ? vt : kt) +
                ((size_t)tb * NN + (which ? m0 : n0) + r) * CC + c0 + s * 8;
            unsigned short (*dst)[72] = which ? Vt : Kt;
            *(short8*)(&dst[r][s * 8]) = *(const short8*)sp;
        }
        __syncthreads();
#pragma unroll
        for (int ksub = 0; ksub < 2; ++ksub) {
            const int co = ksub * 32 + kb * 8;
            short8 a0 = *(const short8*)&Kt[wn * 32 + l16][co];
            short8 a1 = *(const short8*)&Kt[wn * 32 + 16 + l16][co];
            short8 b0 = *(const short8*)&Vt[wm * 32 + l16][co];
            short8 b1 = *(const short8*)&Vt[wm * 32 + 16 + l16][co];
            acc[0][0] = __builtin_amdgcn_mfma_f32_16x16x32_bf16(a0, b0, acc[0][0], 0, 0, 0);
            acc[0][1] = __builtin_amdgcn_mfma_f32_16x16x32_bf16(a0, b1, acc[0][1], 0, 0, 0);
            acc[1][0] = __builtin_amdgcn_mfma_f32_16x16x32_bf16(a1, b0, acc[1][0], 0, 0, 0);
            acc[1][1] = __builtin_amdgcn_mfma_f32_16x16x32_bf16(a1, b1, acc[1][1], 0, 0, 0);
        }
        __syncthreads();
    }
#pragma unroll
    for (int fr = 0; fr < 2; ++fr)
#pragma unroll
        for (int fc = 0; fc < 2; ++fc) {
            int n = n0 + wn * 32 + fr * 16 + kb * 4;
            int m = m0 + wm * 32 + fc * 16 + l16;
            us4 pk;
#pragma unroll
            for (int rg = 0; rg < 4; ++rg) {
                union { _Float16 h; unsigned short u; } cv;
                cv.h = (_Float16)acc[fr][fc][rg];
                pk[rg] = cv.u;
            }
            *(us4*)&kvf[((size_t)tb * NN + m) * NN + n] = pk;
        }
}

// ---------------------------------------------------------------------------
// K3: a[c,m] = 0.125 * sum_n q[c,n] kv[n,m]; LIF(v_th=0.5).  (verbatim)
// ---------------------------------------------------------------------------
__global__ __launch_bounds__(256) void k3_attn(
    const unsigned short* __restrict__ qf, const unsigned short* __restrict__ kvf,
    unsigned short* __restrict__ abf)
{
    const int c0 = blockIdx.x * 64, m0 = blockIdx.y * 64, b = blockIdx.z;
    const int tid = threadIdx.x, lane = tid & 63, wid = tid >> 6;
    const int wc = wid >> 1, wm = wid & 1;
    const int l16 = lane & 15, kb = lane >> 4;
    __shared__ unsigned short Qt[TT][64][40];
    __shared__ unsigned short Mt[TT][64][40];
    f32x4 acc[TT][2][2];
#pragma unroll
    for (int t = 0; t < TT; ++t)
#pragma unroll
        for (int fr = 0; fr < 2; ++fr)
#pragma unroll
            for (int fc = 0; fc < 2; ++fc) acc[t][fr][fc] = (f32x4){0.f, 0.f, 0.f, 0.f};

    for (int ks = 0; ks < 8; ++ks) {
        const int nk0 = ks * 32;
#pragma unroll
        for (int i = tid; i < 2048; i += 256) {
            int which = i >> 10, rem = i & 1023;
            int t = rem >> 8, r = (rem >> 2) & 63, s = rem & 3;
            if (which == 0) {
                const unsigned short* sp = qf + ((size_t)(t * BB + b) * CC + c0 + r) * NN + nk0 + s * 8;
                *(short8*)(&Qt[t][r][s * 8]) = *(const short8*)sp;
            } else {
                const unsigned short* sp = kvf + ((size_t)(t * BB + b) * NN + m0 + r) * NN + nk0 + s * 8;
                *(short8*)(&Mt[t][r][s * 8]) = *(const short8*)sp;
            }
        }
        __syncthreads();
#pragma unroll
        for (int t = 0; t < TT; ++t) {
            h8 a0 = *(const h8*)&Qt[t][wc * 32 + l16][kb * 8];
            h8 a1 = *(const h8*)&Qt[t][wc * 32 + 16 + l16][kb * 8];
            h8 b0 = *(const h8*)&Mt[t][wm * 32 + l16][kb * 8];
            h8 b1 = *(const h8*)&Mt[t][wm * 32 + 16 + l16][kb * 8];
            acc[t][0][0] = __builtin_amdgcn_mfma_f32_16x16x32_f16(a0, b0, acc[t][0][0], 0, 0, 0);
            acc[t][0][1] = __builtin_amdgcn_mfma_f32_16x16x32_f16(a0, b1, acc[t][0][1], 0, 0, 0);
            acc[t][1][0] = __builtin_amdgcn_mfma_f32_16x16x32_f16(a1, b0, acc[t][1][0], 0, 0, 0);
            acc[t][1][1] = __builtin_amdgcn_mfma_f32_16x16x32_f16(a1, b1, acc[t][1][1], 0, 0, 0);
        }
        __syncthreads();
    }

#pragma unroll
    for (int fr = 0; fr < 2; ++fr)
#pragma unroll
        for (int fc = 0; fc < 2; ++fc) {
            const int m = m0 + wm * 32 + fc * 16 + l16;
            const int cbase = c0 + wc * 32 + fr * 16 + kb * 4;
            const int key0 = (m & 1) * 4;
            us4 pk[TT];
#pragma unroll
            for (int rg = 0; rg < 4; ++rg) {
                float vv = 0.f;
#pragma unroll
                for (int t = 0; t < TT; ++t) {
                    float a = acc[t][fr][fc][rg] * 0.125f;
                    vv += (a - vv) * 0.5f;
                    if (vv >= 0.5f) { pk[t][rg] = 0x3F80; vv = 0.f; }
                    else pk[t][rg] = 0;
                }
            }
#pragma unroll
            for (int t = 0; t < TT; ++t)
                *(us4*)&abf[(((size_t)b * NN + m) * TT + t) * CC + csw(cbase, key0 + t)] = pk[t];
        }
}

// ---------------------------------------------------------------------------
extern "C" void kernel_launch(void* const* d_in, const int* in_sizes, int n_in,
                              void* d_out, int out_size, void* d_ws, size_t ws_size,
                              hipStream_t stream)
{
    const float* x    = (const float*)d_in[0];
    const float* q_w  = (const float*)d_in[2];
    const float* k_w  = (const float*)d_in[3];
    const float* v_w  = (const float*)d_in[4];
    const float* q_g  = (const float*)d_in[5];
    const float* q_b  = (const float*)d_in[6];
    const float* q_m  = (const float*)d_in[7];
    const float* q_v  = (const float*)d_in[8];
    const float* k_g  = (const float*)d_in[9];
    const float* k_b  = (const float*)d_in[10];
    const float* k_m  = (const float*)d_in[11];
    const float* k_v  = (const float*)d_in[12];
    const float* v_g  = (const float*)d_in[13];
    const float* v_b  = (const float*)d_in[14];
    const float* v_m  = (const float*)d_in[15];
    const float* v_v  = (const float*)d_in[16];
    const float* p_g  = (const float*)d_in[17];
    const float* p_be = (const float*)d_in[18];
    const float* p_m  = (const float*)d_in[19];
    const float* p_v  = (const float*)d_in[20];
    const float* p_w  = (const float*)d_in[21];
    const float* p_b  = (const float*)d_in[22];

    const size_t ELEMS = (size_t)TT * BB * CC * NN;   // 8388608
    float* out_s2 = (float*)d_out;
    float* out_v  = out_s2 + ELEMS;

    unsigned char* ws8 = (unsigned char*)d_ws;
    unsigned short* xh   = (unsigned short*)ws8;                       // 16.8 MB
    unsigned short* xl   = (unsigned short*)(ws8 + 16777216ull);       // 16.8 MB
    unsigned short* w8   = (unsigned short*)(ws8 + 33554432ull);       // 4.2 MB
    unsigned short* qf16 = (unsigned short*)(ws8 + 37748736ull);       // 16.8 MB
    unsigned short* kt   = (unsigned short*)(ws8 + 54525952ull);       // 16.8 MB
    unsigned short* vt   = (unsigned short*)(ws8 + 71303168ull);       // 16.8 MB
    unsigned short* kvf  = (unsigned short*)(ws8 + 88080384ull);       // 16.8 MB
    unsigned short* abf  = (unsigned short*)(ws8 + 104857600ull);      // 16.8 MB

    const size_t WSZ = (size_t)CC * CC;
    unsigned short* wph = w8 + 6 * WSZ;
    unsigned short* wpl = w8 + 7 * WSZ;

    dim3 blk(256);
    prep_k<<<4608, blk, 0, stream>>>(x, q_w, k_w, v_w, p_w, xh, xl, w8);

    gemm_qkv_f<<<3072, blk, 0, stream>>>(w8, xh, xl,
                                         q_g, q_b, q_m, q_v,
                                         k_g, k_b, k_m, k_v,
                                         v_g, v_b, v_m, v_v,
                                         q_w, k_w, v_w, x,
                                         qf16, kt, vt, out_v);

    k2_kv<<<dim3(4, 4, 64), blk, 0, stream>>>(kt, vt, kvf);
    k3_attn<<<dim3(8, 4, 16), blk, 0, stream>>>(qf16, kvf, abf);

    gemm_p_f<<<1024, blk, 0, stream>>>(wph, wpl, abf,
                                       p_g, p_be, p_m, p_v, p_b, p_w,
                                       abf, out_s2);
}

// Round 8
// 182.383 us; speedup vs baseline: 1.0514x; 1.0514x over previous
//
#include <hip/hip_runtime.h>
#include <hip/hip_bf16.h>

#define TT 4
#define BB 16
#define CC 512
#define NN 256

typedef short short8 __attribute__((ext_vector_type(8)));
typedef _Float16 h8 __attribute__((ext_vector_type(8)));
typedef float f32x4 __attribute__((ext_vector_type(4)));
typedef float fl4 __attribute__((ext_vector_type(4)));
typedef unsigned short us4 __attribute__((ext_vector_type(4)));

__device__ __forceinline__ unsigned short bf_hi(float x) {
    unsigned u = __float_as_uint(x);
    return (unsigned short)((u + 0x7FFFu + ((u >> 16) & 1u)) >> 16);
}
__device__ __forceinline__ float bf_f(unsigned short h) {
    return __uint_as_float(((unsigned)h) << 16);
}
__device__ __forceinline__ void glds16(const void* g, void* l) {
    __builtin_amdgcn_global_load_lds(
        (const __attribute__((address_space(1))) unsigned int*)g,
        (__attribute__((address_space(3))) unsigned int*)l, 16, 0, 0);
}
// permute 16B slots within each 64-short K-group by (key&7)  [R8-proven]
__device__ __forceinline__ int csw(int c, int rkey) {
    return (c & ~63) | ((((c >> 3) & 7) ^ (rkey & 7)) << 3) | (c & 7);
}

// ---------------------------------------------------------------------------
// prep_k: fused preprocessing.  (verbatim R10)
// ---------------------------------------------------------------------------
__global__ __launch_bounds__(256) void prep_k(
    const float* __restrict__ x,
    const float* __restrict__ w0, const float* __restrict__ w1,
    const float* __restrict__ w2, const float* __restrict__ w3,
    unsigned short* __restrict__ xh, unsigned short* __restrict__ xl,
    unsigned short* __restrict__ wsplit)
{
    const int bid = blockIdx.x;
    const int tid = threadIdx.x;
    if (bid < 4096) {
        __shared__ float Tt[64][33];
        const int tb = bid >> 6, rem = bid & 63;
        const int c0 = (rem >> 3) * 64, n0 = (rem & 7) * 32;
        const int t = tb >> 4, b = tb & 15;
        {
            int row = tid >> 2, seg = tid & 3;
            const float* sp = x + ((size_t)tb * CC + c0 + row) * NN + n0 + seg * 8;
            fl4 v0 = *(const fl4*)sp;
            fl4 v1 = *(const fl4*)(sp + 4);
#pragma unroll
            for (int j = 0; j < 4; ++j) {
                Tt[row][seg * 8 + j] = v0[j];
                Tt[row][seg * 8 + 4 + j] = v1[j];
            }
        }
        __syncthreads();
        {
            int n = tid >> 3, co = tid & 7;
            int c = c0 + co * 8;
            short8 hi, lo;
#pragma unroll
            for (int j = 0; j < 8; ++j) {
                float f = Tt[co * 8 + j][n];
                unsigned short h = bf_hi(f);
                hi[j] = (short)h;
                lo[j] = (short)bf_hi(f - bf_f(h));
            }
            int nn = n0 + n;
            int key = (nn & 1) * 4 + t;
            size_t dst = (((size_t)b * NN + nn) * TT + t) * CC
                       + (c & ~63) + (((((c >> 3) & 7) ^ (key & 7))) << 3);
            *(short8*)(xh + dst) = hi;
            *(short8*)(xl + dst) = lo;
        }
    } else {
        const int wb = bid - 4096;           // [0, 512)
        const int m = wb >> 7;
        const int idx = wb & 127;
        const float* src = (m == 0) ? w0 : (m == 1) ? w1 : (m == 2) ? w2 : w3;
        unsigned short* dh = wsplit + (size_t)m * 2 * CC * CC;
        unsigned short* dl = dh + (size_t)CC * CC;
        const int flat = idx * 2048 + tid * 8;
        const int o = flat >> 9, c = flat & 511;
        const float* sp = src + flat;
        fl4 v0 = *(const fl4*)sp;
        fl4 v1 = *(const fl4*)(sp + 4);
        short8 hi, lo;
#pragma unroll
        for (int j = 0; j < 8; ++j) {
            float f = (j < 4) ? v0[j] : v1[j - 4];
            unsigned short h = bf_hi(f);
            hi[j] = (short)h;
            lo[j] = (short)bf_hi(f - bf_f(h));
        }
        size_t dst = (size_t)o * CC + (c & ~63) + ((((c >> 3) & 7) ^ (o & 7)) << 3);
        *(short8*)(dh + dst) = hi;
        *(short8*)(dl + dst) = lo;
    }
}

// ---------------------------------------------------------------------------
// gemm_qkv_f: fused q/k/v GEMM (3-pass bf16 split) + BN + LIF + fixup.
// R18 = verbatim R16 (best measured, 102-103 us): Al direct-from-global
// (per-wave-disjoint rows); Ah/Bh/Bl staged in 32KB LDS -> 4 blocks/CU.
// grid 3072, block 256.
// ---------------------------------------------------------------------------
__global__ __launch_bounds__(256, 4) void gemm_qkv_f(
    const unsigned short* __restrict__ w8,
    const unsigned short* __restrict__ Bh, const unsigned short* __restrict__ Bl,
    const float* __restrict__ qg, const float* __restrict__ qb,
    const float* __restrict__ qm, const float* __restrict__ qva,
    const float* __restrict__ kg, const float* __restrict__ kbe,
    const float* __restrict__ km, const float* __restrict__ kva,
    const float* __restrict__ vg, const float* __restrict__ vb,
    const float* __restrict__ vm, const float* __restrict__ vva,
    const float* __restrict__ qw, const float* __restrict__ kw,
    const float* __restrict__ vw, const float* __restrict__ xf,
    unsigned short* __restrict__ qo, unsigned short* __restrict__ ktr,
    unsigned short* __restrict__ vtr, float* __restrict__ outv)
{
    const int bid = blockIdx.x;
    const int orig = (bid & 7) * 384 + (bid >> 3);
    const int cb = orig / 12;
    const int ob = orig - cb * 12;
    const int mat = ob >> 2;
    const int o0 = (ob & 3) * 128;
    const int col0 = cb * 64;
    const int b  = cb >> 4;
    const int n0 = (cb & 15) * 16;
    const unsigned short* Ah = w8 + (size_t)mat * 2 * CC * CC;
    const unsigned short* Alg = Ah + (size_t)CC * CC;   // A-low, read direct

    const int tid = threadIdx.x, lane = tid & 63, wid = tid >> 6;
    const int l16 = lane & 15, kb = lane >> 4;
    const int sx = l16 & 7;

    __shared__ __align__(16) char raw[32768];   // Ah 16K | Bh 8K | Bl 8K

    // staging: 8 glds16 per wave (balanced)
    const int srow = lane >> 3, sslot = lane & 7;
    const unsigned short* sect =
        (wid == 0) ? Ah + (size_t)o0 * CC :
        (wid == 1) ? Ah + (size_t)(o0 + 64) * CC :
        (wid == 2) ? Bh + (size_t)col0 * CC :
                     Bl + (size_t)col0 * CC;
    const unsigned short* gsrc = sect + (size_t)srow * CC + sslot * 8;
    char* ldsb = raw + wid * 8192;

    f32x4 acc[2][4];
#pragma unroll
    for (int r = 0; r < 2; ++r)
#pragma unroll
        for (int c = 0; c < 4; ++c) acc[r][c] = (f32x4){0.f, 0.f, 0.f, 0.f};

    for (int ks = 0; ks < 8; ++ks) {
        const int k0 = ks * 64;
        // Al fragments direct from global (per-wave-disjoint rows).
        // Address mirrors the old staged+ds_read composite: the ^sx
        // un-swizzles the (o&7) csw applied in prep_k.
        short8 alv[2][2];
#pragma unroll
        for (int ksub = 0; ksub < 2; ++ksub)
#pragma unroll
            for (int r = 0; r < 2; ++r)
                alv[ksub][r] = *(const short8*)(Alg
                    + (size_t)(o0 + wid * 32 + r * 16 + l16) * CC
                    + k0 + (((ksub * 4 + kb) ^ sx) << 3));
        // stage Ah/Bh/Bl into LDS
#pragma unroll
        for (int i = 0; i < 8; ++i)
            glds16(gsrc + (size_t)(i * 8) * CC + k0, ldsb + i * 1024);
        __syncthreads();
#pragma unroll
        for (int ksub = 0; ksub < 2; ++ksub) {
            const int soff = ((ksub * 4 + kb) ^ sx) << 4;
            short8 ah[2], bh[4], bl[4];
#pragma unroll
            for (int r = 0; r < 2; ++r) {
                const int ra = (wid * 32 + r * 16 + l16) * 128 + soff;
                ah[r] = *(const short8*)(raw + ra);
            }
#pragma unroll
            for (int c = 0; c < 4; ++c) {
                const int rb = (c * 16 + l16) * 128 + soff;
                bh[c] = *(const short8*)(raw + 16384 + rb);
                bl[c] = *(const short8*)(raw + 24576 + rb);
            }
#pragma unroll
            for (int r = 0; r < 2; ++r)
#pragma unroll
                for (int c = 0; c < 4; ++c)
                    acc[r][c] = __builtin_amdgcn_mfma_f32_16x16x32_bf16(ah[r], bh[c], acc[r][c], 0, 0, 0);
#pragma unroll
            for (int r = 0; r < 2; ++r)
#pragma unroll
                for (int c = 0; c < 4; ++c)
                    acc[r][c] = __builtin_amdgcn_mfma_f32_16x16x32_bf16(alv[ksub][r], bh[c], acc[r][c], 0, 0, 0);
#pragma unroll
            for (int r = 0; r < 2; ++r)
#pragma unroll
                for (int c = 0; c < 4; ++c)
                    acc[r][c] = __builtin_amdgcn_mfma_f32_16x16x32_bf16(ah[r], bl[c], acc[r][c], 0, 0, 0);
        }
        __syncthreads();
    }

    // ---- epilogue: acc -> LDS y tile [128][64] (XOR-banked) ----
    float* Yf = (float*)raw;
#pragma unroll
    for (int r = 0; r < 2; ++r)
#pragma unroll
        for (int c = 0; c < 4; ++c) {
            const int col = c * 16 + l16;
#pragma unroll
            for (int g = 0; g < 4; ++g) {
                const int row = wid * 32 + r * 16 + kb * 4 + g;
                Yf[row * 64 + (col ^ (((row >> 2) & 7) << 2))] = acc[r][c][g];
            }
        }
    __syncthreads();

    const float* gg = (mat == 0) ? qg : (mat == 1) ? kg : vg;
    const float* be = (mat == 0) ? qb : (mat == 1) ? kbe : vb;
    const float* mu = (mat == 0) ? qm : (mat == 1) ? km : vm;
    const float* va = (mat == 0) ? qva : (mat == 1) ? kva : vva;
    const float* wsel = (mat == 0) ? qw : (mat == 1) ? kw : vw;

    const int lo2  = tid >> 3;
    const int rsel = (tid >> 2) & 1;
    const int ln2  = tid & 3;
    const float M1 = 2e-4f;

    float inv[2], bbv[2];
#pragma unroll
    for (int i = 0; i < 2; ++i) {
        int oo = o0 + lo2 * 4 + rsel * 2 + i;
        double invd = (double)gg[oo] / sqrt((double)va[oo] + 1e-5);
        inv[i] = (float)invd;
        bbv[i] = (float)((double)be[oo] - (double)mu[oo] * invd);
    }

    unsigned long long s1b = 0;
    unsigned fmask = 0;
#pragma unroll
    for (int i = 0; i < 2; ++i) {
        const int row = lo2 * 4 + rsel * 2 + i;
        const int rk = ((row >> 2) & 7) << 2;
#pragma unroll
        for (int j = 0; j < 4; ++j) {
            fl4 yv = *(const fl4*)&Yf[row * 64 + (((ln2 * 4 + j) * 4) ^ rk)];
            float vv = 0.f;
#pragma unroll
            for (int t = 0; t < TT; ++t) {
                float yy = yv[t] * inv[i] + bbv[i];
                vv += (yy - vv) * 0.5f;
                float d = vv - 1.0f;
                if (d < M1 && d > -M1) fmask |= 1u << (i * 4 + j);
                if (d >= 0.0f) { s1b |= 1ull << ((i * 4 + j) * 4 + t); vv = 0.f; }
            }
        }
    }

    unsigned long long ball = __ballot(fmask != 0);
    while (ball) {
        int src = __ffsll(ball) - 1;
        ball &= ball - 1;
        unsigned fm = (unsigned)__shfl((int)fmask, src);
        int slo2 = wid * 8 + (src >> 3);
        int srsel = (src >> 2) & 1, sln = src & 3;
        while (fm) {
            int cell = __ffs(fm) - 1;
            fm &= fm - 1;
            int ci = cell >> 2, cj = cell & 3;
            int oo = o0 + slo2 * 4 + srsel * 2 + ci, nn = n0 + sln * 4 + cj;
            double a0 = 0, a1 = 0, a2 = 0, a3 = 0;
            const float* wrow = wsel + (size_t)oo * CC;
            for (int c = lane; c < CC; c += 64) {
                double wv = (double)wrow[c];
                a0 += wv * (double)xf[(((size_t)(0 * BB + b) * CC + c) * NN) + nn];
                a1 += wv * (double)xf[(((size_t)(1 * BB + b) * CC + c) * NN) + nn];
                a2 += wv * (double)xf[(((size_t)(2 * BB + b) * CC + c) * NN) + nn];
                a3 += wv * (double)xf[(((size_t)(3 * BB + b) * CC + c) * NN) + nn];
            }
#pragma unroll
            for (int off = 32; off > 0; off >>= 1) {
                a0 += __shfl_xor(a0, off);
                a1 += __shfl_xor(a1, off);
                a2 += __shfl_xor(a2, off);
                a3 += __shfl_xor(a3, off);
            }
            if (lane == src) {
                double inv_ = (double)gg[oo] / sqrt((double)va[oo] + 1e-5);
                double bb_  = (double)be[oo] - (double)mu[oo] * inv_;
                s1b &= ~(0xFull << (cell * 4));
                double aa[4] = {a0, a1, a2, a3};
                double vv = 0.0;
#pragma unroll
                for (int t = 0; t < TT; ++t) {
                    double yy = aa[t] * inv_ + bb_;
                    vv += (yy - vv) * 0.5;
                    if (vv >= 1.0) { s1b |= 1ull << (cell * 4 + t); vv = 0.0; }
                }
            }
        }
    }

    // ---- stores ----
    if (mat == 0) {
#pragma unroll
        for (int t = 0; t < TT; ++t) {
            const size_t tb = (size_t)(t * BB + b);
#pragma unroll
            for (int i = 0; i < 2; ++i) {
                us4 pk;
#pragma unroll
                for (int j = 0; j < 4; ++j)
                    pk[j] = ((s1b >> ((i * 4 + j) * 4 + t)) & 1ull) ? (unsigned short)0x3C00 : (unsigned short)0;
                *(us4*)(qo + (tb * CC + o0 + lo2 * 4 + rsel * 2 + i) * NN + n0 + ln2 * 4) = pk;
            }
        }
    } else {
        unsigned short* tr = (mat == 1) ? ktr : vtr;
        unsigned short* Tss = (unsigned short*)raw;   // [4][16][136]
        __syncthreads();
#pragma unroll
        for (int t = 0; t < TT; ++t)
#pragma unroll
            for (int j = 0; j < 4; ++j) {
                unsigned p0 = ((s1b >> ((0 * 4 + j) * 4 + t)) & 1ull) ? 0x3F80u : 0u;
                unsigned p1 = ((s1b >> ((1 * 4 + j) * 4 + t)) & 1ull) ? 0x3F80u : 0u;
                *(unsigned*)&Tss[t * 2176 + (ln2 * 4 + j) * 136 + lo2 * 4 + rsel * 2] =
                    p0 | (p1 << 16);
            }
        __syncthreads();
        {
            const int nrow = tid >> 4, seg = tid & 15;
#pragma unroll
            for (int t = 0; t < TT; ++t) {
                const unsigned short* sp = Tss + t * 2176 + nrow * 136 + seg * 8;
                short8 w0 = *(const short8*)sp;
                unsigned short* dst = tr + ((size_t)(t * BB + b) * NN + n0 + nrow) * CC + o0 + seg * 8;
                *(short8*)dst = w0;
            }
        }
        if (mat == 2) {
#pragma unroll
            for (int t = 0; t < TT; ++t) {
                const size_t tb = (size_t)(t * BB + b);
#pragma unroll
                for (int i = 0; i < 2; ++i) {
                    fl4 f;
#pragma unroll
                    for (int j = 0; j < 4; ++j)
                        f[j] = ((s1b >> ((i * 4 + j) * 4 + t)) & 1ull) ? 1.f : 0.f;
                    *(fl4*)(outv + (tb * CC + o0 + lo2 * 4 + rsel * 2 + i) * NN + n0 + ln2 * 4) = f;
                }
            }
        }
    }
}

// ---------------------------------------------------------------------------
// gemm_p_f: projection GEMM (2-pass) + BN + double-LIF + fixup, fused.
// R18 = verbatim R16/R15 (proven ~-4.5us vs R10): Al direct per-wave global
// loads; Ah 16K + Bh 8K staged (decl 32K for Yf). grid 1024, block 256.
// ---------------------------------------------------------------------------
__global__ __launch_bounds__(256) void gemm_p_f(
    const unsigned short* __restrict__ Ah, const unsigned short* __restrict__ Al,
    const unsigned short* __restrict__ Bhb,
    const float* __restrict__ gg, const float* __restrict__ be,
    const float* __restrict__ mu, const float* __restrict__ va,
    const float* __restrict__ pb, const float* __restrict__ pw,
    const unsigned short* __restrict__ abf, float* __restrict__ out)
{
    const int bid = blockIdx.x;
    const int orig = (bid & 7) * 128 + (bid >> 3);
    const int ob = orig & 3, cb = orig >> 2;
    const int o0 = ob * 128, col0 = cb * 64;
    const int b = cb >> 4, n0 = (cb & 15) * 16;
    const int tid = threadIdx.x, lane = tid & 63, wid = tid >> 6;
    const int l16 = lane & 15, kb = lane >> 4;
    const int sx = l16 & 7;

    __shared__ __align__(16) char raw[32768];   // Ah 16K | Bh 8K (+Yf epi)

    const int srow = lane >> 3, sslot = lane & 7;
    const unsigned short* gsrc;
    char* ldsb;
    int nglds;
    if (wid == 0)      { gsrc = Ah + (size_t)o0 * CC;        ldsb = raw;         nglds = 8; }
    else if (wid == 1) { gsrc = Ah + (size_t)(o0 + 64) * CC; ldsb = raw + 8192;  nglds = 8; }
    else if (wid == 2) { gsrc = Bhb + (size_t)col0 * CC;     ldsb = raw + 16384; nglds = 4; }
    else               { gsrc = Bhb + (size_t)(col0 + 32) * CC; ldsb = raw + 20480; nglds = 4; }
    gsrc += (size_t)srow * CC + sslot * 8;

    f32x4 acc[2][4];
#pragma unroll
    for (int r = 0; r < 2; ++r)
#pragma unroll
        for (int c = 0; c < 4; ++c) acc[r][c] = (f32x4){0.f, 0.f, 0.f, 0.f};

    for (int ks = 0; ks < 8; ++ks) {
        const int k0 = ks * 64;
        short8 alv[2][2];
#pragma unroll
        for (int ksub = 0; ksub < 2; ++ksub) {
            const int kof = k0 + (((ksub * 4 + kb) ^ sx) << 3);
#pragma unroll
            for (int r = 0; r < 2; ++r)
                alv[ksub][r] = *(const short8*)(Al
                    + (size_t)(o0 + wid * 32 + r * 16 + l16) * CC + kof);
        }
#pragma unroll
        for (int i = 0; i < 8; ++i)
            if (i < nglds)
                glds16(gsrc + (size_t)(i * 8) * CC + k0, ldsb + i * 1024);
        __syncthreads();
#pragma unroll
        for (int ksub = 0; ksub < 2; ++ksub) {
            const int soff = ((ksub * 4 + kb) ^ sx) << 4;
            short8 ah[2], bh[4];
#pragma unroll
            for (int r = 0; r < 2; ++r) {
                const int ra = (wid * 32 + r * 16 + l16) * 128 + soff;
                ah[r] = *(const short8*)(raw + ra);
            }
#pragma unroll
            for (int c = 0; c < 4; ++c) {
                const int rb = (c * 16 + l16) * 128 + soff;
                bh[c] = *(const short8*)(raw + 16384 + rb);
            }
#pragma unroll
            for (int r = 0; r < 2; ++r)
#pragma unroll
                for (int c = 0; c < 4; ++c)
                    acc[r][c] = __builtin_amdgcn_mfma_f32_16x16x32_bf16(ah[r], bh[c], acc[r][c], 0, 0, 0);
#pragma unroll
            for (int r = 0; r < 2; ++r)
#pragma unroll
                for (int c = 0; c < 4; ++c)
                    acc[r][c] = __builtin_amdgcn_mfma_f32_16x16x32_bf16(alv[ksub][r], bh[c], acc[r][c], 0, 0, 0);
        }
        __syncthreads();
    }

    // ---- epilogue ----
    float* Yf = (float*)raw;
#pragma unroll
    for (int r = 0; r < 2; ++r)
#pragma unroll
        for (int c = 0; c < 4; ++c) {
            const int col = c * 16 + l16;
#pragma unroll
            for (int g = 0; g < 4; ++g) {
                const int row = wid * 32 + r * 16 + kb * 4 + g;
                Yf[row * 64 + (col ^ (((row >> 2) & 7) << 2))] = acc[r][c][g];
            }
        }
    __syncthreads();

    const int lo2  = tid >> 3;
    const int rsel = (tid >> 2) & 1;
    const int ln2  = tid & 3;
    const float M1 = 2e-4f;

    float inv[2], bbv[2], pbo[2];
#pragma unroll
    for (int i = 0; i < 2; ++i) {
        int oo = o0 + lo2 * 4 + rsel * 2 + i;
        double invd = (double)gg[oo] / sqrt((double)va[oo] + 1e-5);
        inv[i] = (float)invd;
        bbv[i] = (float)((double)be[oo] - (double)mu[oo] * invd);
        pbo[i] = pb[oo];
    }

    unsigned long long s2b = 0;
    unsigned fmask = 0;
#pragma unroll
    for (int i = 0; i < 2; ++i) {
        const int row = lo2 * 4 + rsel * 2 + i;
        const int rk = ((row >> 2) & 7) << 2;
#pragma unroll
        for (int j = 0; j < 4; ++j) {
            fl4 yv = *(const fl4*)&Yf[row * 64 + (((ln2 * 4 + j) * 4) ^ rk)];
            float vv = 0.f;
            unsigned s1loc = 0;
#pragma unroll
            for (int t = 0; t < TT; ++t) {
                float yy = (yv[t] + pbo[i]) * inv[i] + bbv[i];
                vv += (yy - vv) * 0.5f;
                float d = vv - 1.0f;
                if (d < M1 && d > -M1) fmask |= 1u << (i * 4 + j);
                if (d >= 0.0f) { s1loc |= 1u << t; vv = 0.f; }
            }
            float v2 = vv;
#pragma unroll
            for (int t = 0; t < TT; ++t) {
                float s1 = ((s1loc >> t) & 1u) ? 1.f : 0.f;
                v2 += (s1 - v2) * 0.5f;
                float d = v2 - 1.0f;
                if (d < M1 && d > -M1) fmask |= 1u << (i * 4 + j);
                if (d >= 0.0f) { s2b |= 1ull << ((i * 4 + j) * 4 + t); v2 = 0.f; }
            }
        }
    }

    unsigned long long ball = __ballot(fmask != 0);
    while (ball) {
        int src = __ffsll(ball) - 1;
        ball &= ball - 1;
        unsigned fm = (unsigned)__shfl((int)fmask, src);
        int slo2 = wid * 8 + (src >> 3);
        int srsel = (src >> 2) & 1, sln = src & 3;
        while (fm) {
            int cell = __ffs(fm) - 1;
            fm &= fm - 1;
            int ci = cell >> 2, cj = cell & 3;
            int oo = o0 + slo2 * 4 + srsel * 2 + ci, nn = n0 + sln * 4 + cj;
            double a0 = 0, a1 = 0, a2 = 0, a3 = 0;
            const float* wrow = pw + (size_t)oo * CC;
            const int key0 = (nn & 1) * 4;
            for (int c = lane; c < CC; c += 64) {
                double wv = (double)wrow[c];
                size_t rb = ((size_t)b * NN + nn) * TT;
                if (abf[(rb + 0) * CC + csw(c, key0 + 0)]) a0 += wv;
                if (abf[(rb + 1) * CC + csw(c, key0 + 1)]) a1 += wv;
                if (abf[(rb + 2) * CC + csw(c, key0 + 2)]) a2 += wv;
                if (abf[(rb + 3) * CC + csw(c, key0 + 3)]) a3 += wv;
            }
#pragma unroll
            for (int off = 32; off > 0; off >>= 1) {
                a0 += __shfl_xor(a0, off);
                a1 += __shfl_xor(a1, off);
                a2 += __shfl_xor(a2, off);
                a3 += __shfl_xor(a3, off);
            }
            if (lane == src) {
                double inv_ = (double)gg[oo] / sqrt((double)va[oo] + 1e-5);
                double bb_  = (double)be[oo] - (double)mu[oo] * inv_;
                double pb_  = (double)pb[oo];
                s2b &= ~(0xFull << (cell * 4));
                double aa[4] = {a0, a1, a2, a3};
                double vv = 0.0;
                unsigned s1loc = 0;
#pragma unroll
                for (int t = 0; t < TT; ++t) {
                    double yy = (aa[t] + pb_) * inv_ + bb_;
                    vv += (yy - vv) * 0.5;
                    if (vv >= 1.0) { s1loc |= 1u << t; vv = 0.0; }
                }
                double v2 = vv;
#pragma unroll
                for (int t = 0; t < TT; ++t) {
                    double s1 = ((s1loc >> t) & 1u) ? 1.0 : 0.0;
                    v2 += (s1 - v2) * 0.5;
                    if (v2 >= 1.0) { s2b |= 1ull << (cell * 4 + t); v2 = 0.0; }
                }
            }
        }
    }

#pragma unroll
    for (int t = 0; t < TT; ++t) {
        const size_t tb = (size_t)(t * BB + b);
#pragma unroll
        for (int i = 0; i < 2; ++i) {
            fl4 f;
#pragma unroll
            for (int j = 0; j < 4; ++j)
                f[j] = ((s2b >> ((i * 4 + j) * 4 + t)) & 1ull) ? 1.f : 0.f;
            *(fl4*)(out + (tb * CC + o0 + lo2 * 4 + rsel * 2 + i) * NN + n0 + ln2 * 4) = f;
        }
    }
}

// ---------------------------------------------------------------------------
// K2: kv[n,m] = sum_c kT[n,c] vT[m,c] (binary bf16, exact).
// R18: 1-D grid 1024 with XCD-aware decode — all 16 (m0,n0) blocks of one
// tb share bid&7, so one XCD's L2 holds that tb's kt/vt panels once.
// ---------------------------------------------------------------------------
__global__ __launch_bounds__(256) void k2_kv(
    const unsigned short* __restrict__ kt, const unsigned short* __restrict__ vt,
    unsigned short* __restrict__ kvf)
{
    const int bid = blockIdx.x;
    const int rest = bid >> 3;                 // [0,128)
    const int tb = (bid & 7) + 8 * (rest >> 4);   // [0,64)
    const int mn = rest & 15;
    const int m0 = (mn & 3) * 64, n0 = (mn >> 2) * 64;
    const int tid = threadIdx.x, lane = tid & 63, wid = tid >> 6;
    const int wn = wid >> 1, wm = wid & 1;
    const int l16 = lane & 15, kb = lane >> 4;
    __shared__ unsigned short Kt[64][72];
    __shared__ unsigned short Vt[64][72];
    f32x4 acc[2][2];
#pragma unroll
    for (int a = 0; a < 2; ++a)
#pragma unroll
        for (int c = 0; c < 2; ++c) acc[a][c] = (f32x4){0.f, 0.f, 0.f, 0.f};

    for (int ks = 0; ks < 8; ++ks) {
        const int c0 = ks * 64;
#pragma unroll
        for (int i = tid; i < 1024; i += 256) {
            int which = i >> 9, r = (i >> 3) & 63, s = i & 7;
            const unsigned short* sp = (which ? vt : kt) +
                ((size_t)tb * NN + (which ? m0 : n0) + r) * CC + c0 + s * 8;
            unsigned short (*dst)[72] = which ? Vt : Kt;
            *(short8*)(&dst[r][s * 8]) = *(const short8*)sp;
        }
        __syncthreads();
#pragma unroll
        for (int ksub = 0; ksub < 2; ++ksub) {
            const int co = ksub * 32 + kb * 8;
            short8 a0 = *(const short8*)&Kt[wn * 32 + l16][co];
            short8 a1 = *(const short8*)&Kt[wn * 32 + 16 + l16][co];
            short8 b0 = *(const short8*)&Vt[wm * 32 + l16][co];
            short8 b1 = *(const short8*)&Vt[wm * 32 + 16 + l16][co];
            acc[0][0] = __builtin_amdgcn_mfma_f32_16x16x32_bf16(a0, b0, acc[0][0], 0, 0, 0);
            acc[0][1] = __builtin_amdgcn_mfma_f32_16x16x32_bf16(a0, b1, acc[0][1], 0, 0, 0);
            acc[1][0] = __builtin_amdgcn_mfma_f32_16x16x32_bf16(a1, b0, acc[1][0], 0, 0, 0);
            acc[1][1] = __builtin_amdgcn_mfma_f32_16x16x32_bf16(a1, b1, acc[1][1], 0, 0, 0);
        }
        __syncthreads();
    }
#pragma unroll
    for (int fr = 0; fr < 2; ++fr)
#pragma unroll
        for (int fc = 0; fc < 2; ++fc) {
            int n = n0 + wn * 32 + fr * 16 + kb * 4;
            int m = m0 + wm * 32 + fc * 16 + l16;
            us4 pk;
#pragma unroll
            for (int rg = 0; rg < 4; ++rg) {
                union { _Float16 h; unsigned short u; } cv;
                cv.h = (_Float16)acc[fr][fc][rg];
                pk[rg] = cv.u;
            }
            *(us4*)&kvf[((size_t)tb * NN + m) * NN + n] = pk;
        }
}

// ---------------------------------------------------------------------------
// K3: a[c,m] = 0.125 * sum_n q[c,n] kv[n,m]; LIF(v_th=0.5).
// R18: 1-D grid 512 with XCD-aware decode — all 32 (c0,m0) blocks of one
// b share bid&7 (same-XCD L2 reuse of qf/kvf panels).
// ---------------------------------------------------------------------------
__global__ __launch_bounds__(256) void k3_attn(
    const unsigned short* __restrict__ qf, const unsigned short* __restrict__ kvf,
    unsigned short* __restrict__ abf)
{
    const int bid = blockIdx.x;
    const int rest = bid >> 3;                 // [0,64)
    const int b = (bid & 7) + 8 * (rest >> 5); // [0,16)
    const int cm = rest & 31;
    const int c0 = (cm & 7) * 64, m0 = (cm >> 3) * 64;
    const int tid = threadIdx.x, lane = tid & 63, wid = tid >> 6;
    const int wc = wid >> 1, wm = wid & 1;
    const int l16 = lane & 15, kb = lane >> 4;
    __shared__ unsigned short Qt[TT][64][40];
    __shared__ unsigned short Mt[TT][64][40];
    f32x4 acc[TT][2][2];
#pragma unroll
    for (int t = 0; t < TT; ++t)
#pragma unroll
        for (int fr = 0; fr < 2; ++fr)
#pragma unroll
            for (int fc = 0; fc < 2; ++fc) acc[t][fr][fc] = (f32x4){0.f, 0.f, 0.f, 0.f};

    for (int ks = 0; ks < 8; ++ks) {
        const int nk0 = ks * 32;
#pragma unroll
        for (int i = tid; i < 2048; i += 256) {
            int which = i >> 10, rem = i & 1023;
            int t = rem >> 8, r = (rem >> 2) & 63, s = rem & 3;
            if (which == 0) {
                const unsigned short* sp = qf + ((size_t)(t * BB + b) * CC + c0 + r) * NN + nk0 + s * 8;
                *(short8*)(&Qt[t][r][s * 8]) = *(const short8*)sp;
            } else {
                const unsigned short* sp = kvf + ((size_t)(t * BB + b) * NN + m0 + r) * NN + nk0 + s * 8;
                *(short8*)(&Mt[t][r][s * 8]) = *(const short8*)sp;
            }
        }
        __syncthreads();
#pragma unroll
        for (int t = 0; t < TT; ++t) {
            h8 a0 = *(const h8*)&Qt[t][wc * 32 + l16][kb * 8];
            h8 a1 = *(const h8*)&Qt[t][wc * 32 + 16 + l16][kb * 8];
            h8 b0 = *(const h8*)&Mt[t][wm * 32 + l16][kb * 8];
            h8 b1 = *(const h8*)&Mt[t][wm * 32 + 16 + l16][kb * 8];
            acc[t][0][0] = __builtin_amdgcn_mfma_f32_16x16x32_f16(a0, b0, acc[t][0][0], 0, 0, 0);
            acc[t][0][1] = __builtin_amdgcn_mfma_f32_16x16x32_f16(a0, b1, acc[t][0][1], 0, 0, 0);
            acc[t][1][0] = __builtin_amdgcn_mfma_f32_16x16x32_f16(a1, b0, acc[t][1][0], 0, 0, 0);
            acc[t][1][1] = __builtin_amdgcn_mfma_f32_16x16x32_f16(a1, b1, acc[t][1][1], 0, 0, 0);
        }
        __syncthreads();
    }

#pragma unroll
    for (int fr = 0; fr < 2; ++fr)
#pragma unroll
        for (int fc = 0; fc < 2; ++fc) {
            const int m = m0 + wm * 32 + fc * 16 + l16;
            const int cbase = c0 + wc * 32 + fr * 16 + kb * 4;
            const int key0 = (m & 1) * 4;
            us4 pk[TT];
#pragma unroll
            for (int rg = 0; rg < 4; ++rg) {
                float vv = 0.f;
#pragma unroll
                for (int t = 0; t < TT; ++t) {
                    float a = acc[t][fr][fc][rg] * 0.125f;
                    vv += (a - vv) * 0.5f;
                    if (vv >= 0.5f) { pk[t][rg] = 0x3F80; vv = 0.f; }
                    else pk[t][rg] = 0;
                }
            }
#pragma unroll
            for (int t = 0; t < TT; ++t)
                *(us4*)&abf[(((size_t)b * NN + m) * TT + t) * CC + csw(cbase, key0 + t)] = pk[t];
        }
}

// ---------------------------------------------------------------------------
extern "C" void kernel_launch(void* const* d_in, const int* in_sizes, int n_in,
                              void* d_out, int out_size, void* d_ws, size_t ws_size,
                              hipStream_t stream)
{
    const float* x    = (const float*)d_in[0];
    const float* q_w  = (const float*)d_in[2];
    const float* k_w  = (const float*)d_in[3];
    const float* v_w  = (const float*)d_in[4];
    const float* q_g  = (const float*)d_in[5];
    const float* q_b  = (const float*)d_in[6];
    const float* q_m  = (const float*)d_in[7];
    const float* q_v  = (const float*)d_in[8];
    const float* k_g  = (const float*)d_in[9];
    const float* k_b  = (const float*)d_in[10];
    const float* k_m  = (const float*)d_in[11];
    const float* k_v  = (const float*)d_in[12];
    const float* v_g  = (const float*)d_in[13];
    const float* v_b  = (const float*)d_in[14];
    const float* v_m  = (const float*)d_in[15];
    const float* v_v  = (const float*)d_in[16];
    const float* p_g  = (const float*)d_in[17];
    const float* p_be = (const float*)d_in[18];
    const float* p_m  = (const float*)d_in[19];
    const float* p_v  = (const float*)d_in[20];
    const float* p_w  = (const float*)d_in[21];
    const float* p_b  = (const float*)d_in[22];

    const size_t ELEMS = (size_t)TT * BB * CC * NN;   // 8388608
    float* out_s2 = (float*)d_out;
    float* out_v  = out_s2 + ELEMS;

    unsigned char* ws8 = (unsigned char*)d_ws;
    unsigned short* xh   = (unsigned short*)ws8;                       // 16.8 MB
    unsigned short* xl   = (unsigned short*)(ws8 + 16777216ull);       // 16.8 MB
    unsigned short* w8   = (unsigned short*)(ws8 + 33554432ull);       // 4.2 MB
    unsigned short* qf16 = (unsigned short*)(ws8 + 37748736ull);       // 16.8 MB
    unsigned short* kt   = (unsigned short*)(ws8 + 54525952ull);       // 16.8 MB
    unsigned short* vt   = (unsigned short*)(ws8 + 71303168ull);       // 16.8 MB
    unsigned short* kvf  = (unsigned short*)(ws8 + 88080384ull);       // 16.8 MB
    unsigned short* abf  = (unsigned short*)(ws8 + 104857600ull);      // 16.8 MB

    const size_t WSZ = (size_t)CC * CC;
    unsigned short* wph = w8 + 6 * WSZ;
    unsigned short* wpl = w8 + 7 * WSZ;

    dim3 blk(256);
    prep_k<<<4608, blk, 0, stream>>>(x, q_w, k_w, v_w, p_w, xh, xl, w8);

    gemm_qkv_f<<<3072, blk, 0, stream>>>(w8, xh, xl,
                                         q_g, q_b, q_m, q_v,
                                         k_g, k_b, k_m, k_v,
                                         v_g, v_b, v_m, v_v,
                                         q_w, k_w, v_w, x,
                                         qf16, kt, vt, out_v);

    k2_kv<<<1024, blk, 0, stream>>>(kt, vt, kvf);
    k3_attn<<<512, blk, 0, stream>>>(qf16, kvf, abf);

    gemm_p_f<<<1024, blk, 0, stream>>>(wph, wpl, abf,
                                       p_g, p_be, p_m, p_v, p_b, p_w,
                                       abf, out_s2);
}